// Round 1
// baseline (2581.103 us; speedup 1.0000x reference)
//
#include <hip/hip_runtime.h>
#include <hip/hip_bf16.h>

#define BB 128
#define LC 256
#define LE 1024
#define DD 256
#define MM 512

// ---------- helpers ----------
__device__ __forceinline__ float bfu2f(unsigned short u) {
  return __uint_as_float(((unsigned int)u) << 16);
}
__device__ __forceinline__ unsigned short f2bfu(float f) {
  unsigned int x = __float_as_uint(f);
  return (unsigned short)((x + 0x7fffu + ((x >> 16) & 1u)) >> 16);
}

// ---------- zero fill ----------
__global__ void zero_kernel(float* __restrict__ p, int n) {
  int i = blockIdx.x * 256 + threadIdx.x;
  if (i < n) p[i] = 0.f;
}

// ---------- projection: out = relu(A @ W + bias), A (Mx256) fp32, W (256x256), out bf16 ----------
__global__ void proj_kernel(const float* __restrict__ A, const float* __restrict__ W,
                            const float* __restrict__ bias, unsigned short* __restrict__ out) {
  __shared__ float As[16][65];  // [k][m]
  __shared__ float Bs[16][65];  // [k][n]
  const int tid = threadIdx.x, tx = tid & 15, ty = tid >> 4;
  const size_t m0 = (size_t)blockIdx.y * 64;
  const int n0 = blockIdx.x * 64;
  float acc[4][4] = {};
  for (int k0 = 0; k0 < DD; k0 += 16) {
    const int r = tid >> 2, kk = (tid & 3) * 4;
    float4 va = *(const float4*)(A + (m0 + r) * DD + k0 + kk);
    As[kk + 0][r] = va.x; As[kk + 1][r] = va.y; As[kk + 2][r] = va.z; As[kk + 3][r] = va.w;
    const int kw = tid >> 4, nn = (tid & 15) * 4;
    float4 vb = *(const float4*)(W + (size_t)(k0 + kw) * DD + n0 + nn);
    Bs[kw][nn + 0] = vb.x; Bs[kw][nn + 1] = vb.y; Bs[kw][nn + 2] = vb.z; Bs[kw][nn + 3] = vb.w;
    __syncthreads();
#pragma unroll
    for (int k = 0; k < 16; ++k) {
      float a[4], b[4];
#pragma unroll
      for (int i = 0; i < 4; ++i) a[i] = As[k][ty * 4 + i];
#pragma unroll
      for (int j = 0; j < 4; ++j) b[j] = Bs[k][tx * 4 + j];
#pragma unroll
      for (int i = 0; i < 4; ++i)
#pragma unroll
        for (int j = 0; j < 4; ++j) acc[i][j] += a[i] * b[j];
    }
    __syncthreads();
  }
#pragma unroll
  for (int i = 0; i < 4; ++i) {
    size_t m = m0 + ty * 4 + i;
#pragma unroll
    for (int j = 0; j < 4; ++j) {
      int n = n0 + tx * 4 + j;
      float v = acc[i][j] + bias[n];
      out[m * DD + n] = f2bfu(v > 0.f ? v : 0.f);
    }
  }
}

// ---------- align[b,l,e] = sum_d c[b,l,d]*e[b,e,d], bf16 in/out ----------
__global__ void align_kernel(const unsigned short* __restrict__ cB,
                             const unsigned short* __restrict__ eB,
                             unsigned short* __restrict__ alignB) {
  __shared__ float As[16][65];  // [k=d][m=l]
  __shared__ float Bs[16][65];  // [k=d][n=e]
  const int tid = threadIdx.x, tx = tid & 15, ty = tid >> 4;
  const int b = blockIdx.z;
  const int l0 = blockIdx.y * 64, e0 = blockIdx.x * 64;
  const unsigned short* Ab = cB + (size_t)b * LC * DD;
  const unsigned short* Eb = eB + (size_t)b * LE * DD;
  float acc[4][4] = {};
  for (int k0 = 0; k0 < DD; k0 += 16) {
    const int r = tid >> 2, kk = (tid & 3) * 4;
    ushort4 va = *(const ushort4*)(Ab + (size_t)(l0 + r) * DD + k0 + kk);
    As[kk + 0][r] = bfu2f(va.x); As[kk + 1][r] = bfu2f(va.y);
    As[kk + 2][r] = bfu2f(va.z); As[kk + 3][r] = bfu2f(va.w);
    ushort4 vb = *(const ushort4*)(Eb + (size_t)(e0 + r) * DD + k0 + kk);
    Bs[kk + 0][r] = bfu2f(vb.x); Bs[kk + 1][r] = bfu2f(vb.y);
    Bs[kk + 2][r] = bfu2f(vb.z); Bs[kk + 3][r] = bfu2f(vb.w);
    __syncthreads();
#pragma unroll
    for (int k = 0; k < 16; ++k) {
      float a[4], bb[4];
#pragma unroll
      for (int i = 0; i < 4; ++i) a[i] = As[k][ty * 4 + i];
#pragma unroll
      for (int j = 0; j < 4; ++j) bb[j] = Bs[k][tx * 4 + j];
#pragma unroll
      for (int i = 0; i < 4; ++i)
#pragma unroll
        for (int j = 0; j < 4; ++j) acc[i][j] += a[i] * bb[j];
    }
    __syncthreads();
  }
#pragma unroll
  for (int i = 0; i < 4; ++i) {
    size_t l = l0 + ty * 4 + i;
#pragma unroll
    for (int j = 0; j < 4; ++j) {
      int e = e0 + tx * 4 + j;
      alignB[((size_t)b * LC + l) * LE + e] = f2bfu(acc[i][j]);
    }
  }
}

// ---------- alpha stats: per (b,l) max & sum of exp over Le (masked by ehr_mask) ----------
__global__ void astats_kernel(const unsigned short* __restrict__ alignB,
                              const int* __restrict__ em,
                              float* __restrict__ amax, float* __restrict__ asum) {
  const int b = blockIdx.y, l = blockIdx.x, tid = threadIdx.x;
  const unsigned short* row = alignB + ((size_t)b * LC + l) * LE;
  const int* emb = em + b * LE;
  float vals[4];
  float m = -1e30f;
#pragma unroll
  for (int i = 0; i < 4; ++i) {
    int e = tid + i * 256;
    float v = bfu2f(row[e]) + (emb[e] ? 0.f : -1e9f);
    vals[i] = v;
    m = fmaxf(m, v);
  }
  __shared__ float red[256];
  red[tid] = m; __syncthreads();
  for (int s = 128; s > 0; s >>= 1) {
    if (tid < s) red[tid] = fmaxf(red[tid], red[tid + s]);
    __syncthreads();
  }
  m = red[0];
  __syncthreads();
  float s = 0.f;
#pragma unroll
  for (int i = 0; i < 4; ++i) s += __expf(vals[i] - m);
  red[tid] = s; __syncthreads();
  for (int st = 128; st > 0; st >>= 1) {
    if (tid < st) red[tid] += red[tid + st];
    __syncthreads();
  }
  if (tid == 0) { amax[b * LC + l] = m; asum[b * LC + l] = red[0]; }
}

// ---------- beta stats: per (b,e) online max & sum over Lc (masked by criteria_mask) ----------
__global__ void bstats_kernel(const unsigned short* __restrict__ alignB,
                              const int* __restrict__ cm,
                              float* __restrict__ bmax, float* __restrict__ bsum) {
  const int b = blockIdx.y;
  const int e = blockIdx.x * 256 + threadIdx.x;
  const int* cmb = cm + b * LC;
  float m = -1e30f, s = 0.f;
  for (int l = 0; l < LC; ++l) {
    float v = bfu2f(alignB[((size_t)b * LC + l) * LE + e]) + (cmb[l] ? 0.f : -1e9f);
    if (v > m) { s = s * __expf(m - v) + 1.f; m = v; }
    else s += __expf(v - m);
  }
  bmax[b * LE + e] = m;
  bsum[b * LE + e] = s;
}

// ---------- att_c[b,l,d] = sum_e alpha[b,l,e]*ehr[b,e,d], out bf16 ----------
__global__ void attc_kernel(const unsigned short* __restrict__ alignB,
                            const float* __restrict__ ehr,
                            const int* __restrict__ em,
                            const float* __restrict__ amax, const float* __restrict__ asum,
                            unsigned short* __restrict__ attc) {
  __shared__ float As[16][65];  // [k=e][m=l]
  __shared__ float Bs[16][65];  // [k=e][n=d]
  const int tid = threadIdx.x, tx = tid & 15, ty = tid >> 4;
  const int b = blockIdx.z;
  const int l0 = blockIdx.y * 64, n0 = blockIdx.x * 64;
  float acc[4][4] = {};
  for (int k0 = 0; k0 < LE; k0 += 16) {
    const int r = tid >> 2, kk = (tid & 3) * 4;
    {
      int l = l0 + r;
      float mx = amax[b * LC + l];
      float rs = 1.f / asum[b * LC + l];
      ushort4 va = *(const ushort4*)(alignB + ((size_t)b * LC + l) * LE + k0 + kk);
      const int* emb = em + b * LE + k0 + kk;
      As[kk + 0][r] = __expf(bfu2f(va.x) + (emb[0] ? 0.f : -1e9f) - mx) * rs;
      As[kk + 1][r] = __expf(bfu2f(va.y) + (emb[1] ? 0.f : -1e9f) - mx) * rs;
      As[kk + 2][r] = __expf(bfu2f(va.z) + (emb[2] ? 0.f : -1e9f) - mx) * rs;
      As[kk + 3][r] = __expf(bfu2f(va.w) + (emb[3] ? 0.f : -1e9f) - mx) * rs;
    }
    {
      const int kw = tid >> 4, nn = (tid & 15) * 4;
      float4 vb = *(const float4*)(ehr + ((size_t)b * LE + k0 + kw) * DD + n0 + nn);
      Bs[kw][nn + 0] = vb.x; Bs[kw][nn + 1] = vb.y; Bs[kw][nn + 2] = vb.z; Bs[kw][nn + 3] = vb.w;
    }
    __syncthreads();
#pragma unroll
    for (int k = 0; k < 16; ++k) {
      float a[4], bb[4];
#pragma unroll
      for (int i = 0; i < 4; ++i) a[i] = As[k][ty * 4 + i];
#pragma unroll
      for (int j = 0; j < 4; ++j) bb[j] = Bs[k][tx * 4 + j];
#pragma unroll
      for (int i = 0; i < 4; ++i)
#pragma unroll
        for (int j = 0; j < 4; ++j) acc[i][j] += a[i] * bb[j];
    }
    __syncthreads();
  }
#pragma unroll
  for (int i = 0; i < 4; ++i) {
    size_t l = l0 + ty * 4 + i;
#pragma unroll
    for (int j = 0; j < 4; ++j) {
      int n = n0 + tx * 4 + j;
      attc[((size_t)b * LC + l) * DD + n] = f2bfu(acc[i][j]);
    }
  }
}

// ---------- att_e[b,e,d] = sum_l beta[b,l,e]*criteria[b,l,d], out bf16 ----------
__global__ void atte_kernel(const unsigned short* __restrict__ alignB,
                            const float* __restrict__ criteria,
                            const int* __restrict__ cm,
                            const float* __restrict__ bmax, const float* __restrict__ bsum,
                            unsigned short* __restrict__ atte) {
  __shared__ float As[16][65];  // [k=l][m=e]
  __shared__ float Bs[16][65];  // [k=l][n=d]
  const int tid = threadIdx.x, tx = tid & 15, ty = tid >> 4;
  const int b = blockIdx.z;
  const int e0 = blockIdx.y * 64, n0 = blockIdx.x * 64;
  const int eA = tid & 63, lb = tid >> 6;
  const float mx = bmax[b * LE + e0 + eA];
  const float rs = 1.f / bsum[b * LE + e0 + eA];
  float acc[4][4] = {};
  for (int k0 = 0; k0 < LC; k0 += 16) {
#pragma unroll
    for (int i = 0; i < 4; ++i) {
      int l = k0 + lb * 4 + i;
      float v = bfu2f(alignB[((size_t)b * LC + l) * LE + e0 + eA]) +
                (cm[b * LC + l] ? 0.f : -1e9f);
      As[lb * 4 + i][eA] = __expf(v - mx) * rs;
    }
    const int kw = tid >> 4, nn = (tid & 15) * 4;
    float4 vb = *(const float4*)(criteria + ((size_t)b * LC + k0 + kw) * DD + n0 + nn);
    Bs[kw][nn + 0] = vb.x; Bs[kw][nn + 1] = vb.y; Bs[kw][nn + 2] = vb.z; Bs[kw][nn + 3] = vb.w;
    __syncthreads();
#pragma unroll
    for (int k = 0; k < 16; ++k) {
      float a[4], bb[4];
#pragma unroll
      for (int i = 0; i < 4; ++i) a[i] = As[k][ty * 4 + i];
#pragma unroll
      for (int j = 0; j < 4; ++j) bb[j] = Bs[k][tx * 4 + j];
#pragma unroll
      for (int i = 0; i < 4; ++i)
#pragma unroll
        for (int j = 0; j < 4; ++j) acc[i][j] += a[i] * bb[j];
    }
    __syncthreads();
  }
#pragma unroll
  for (int i = 0; i < 4; ++i) {
    size_t e = e0 + ty * 4 + i;
#pragma unroll
    for (int j = 0; j < 4; ++j) {
      int n = n0 + tx * 4 + j;
      atte[((size_t)b * LE + e) * DD + n] = f2bfu(acc[i][j]);
    }
  }
}

// ---------- r = sum_seq relu([att, orig] @ Wr + br); att bf16, orig fp32 ----------
__global__ void rsum_kernel(const unsigned short* __restrict__ attB,
                            const float* __restrict__ orig,
                            const float* __restrict__ Wr, const float* __restrict__ br,
                            float* __restrict__ rout, int Lseq) {
  __shared__ float As[16][65];
  __shared__ float Bs[16][65];
  __shared__ float red[16][65];
  const int tid = threadIdx.x, tx = tid & 15, ty = tid >> 4;
  const size_t m0 = (size_t)blockIdx.y * 64;
  const int n0 = blockIdx.x * 64;
  float acc[4][4] = {};
  for (int k0 = 0; k0 < 2 * DD; k0 += 16) {
    const int r = tid >> 2, kk = (tid & 3) * 4;
    if (k0 < DD) {
      ushort4 va = *(const ushort4*)(attB + (m0 + r) * DD + k0 + kk);
      As[kk + 0][r] = bfu2f(va.x); As[kk + 1][r] = bfu2f(va.y);
      As[kk + 2][r] = bfu2f(va.z); As[kk + 3][r] = bfu2f(va.w);
    } else {
      float4 va = *(const float4*)(orig + (m0 + r) * DD + (k0 - DD) + kk);
      As[kk + 0][r] = va.x; As[kk + 1][r] = va.y; As[kk + 2][r] = va.z; As[kk + 3][r] = va.w;
    }
    const int kw = tid >> 4, nn = (tid & 15) * 4;
    float4 vb = *(const float4*)(Wr + (size_t)(k0 + kw) * DD + n0 + nn);
    Bs[kw][nn + 0] = vb.x; Bs[kw][nn + 1] = vb.y; Bs[kw][nn + 2] = vb.z; Bs[kw][nn + 3] = vb.w;
    __syncthreads();
#pragma unroll
    for (int k = 0; k < 16; ++k) {
      float a[4], bb[4];
#pragma unroll
      for (int i = 0; i < 4; ++i) a[i] = As[k][ty * 4 + i];
#pragma unroll
      for (int j = 0; j < 4; ++j) bb[j] = Bs[k][tx * 4 + j];
#pragma unroll
      for (int i = 0; i < 4; ++i)
#pragma unroll
        for (int j = 0; j < 4; ++j) acc[i][j] += a[i] * bb[j];
    }
    __syncthreads();
  }
  const int b = (int)(m0 / Lseq);
  float cs[4];
#pragma unroll
  for (int j = 0; j < 4; ++j) {
    float s = 0.f;
    float bias = br[n0 + tx * 4 + j];
#pragma unroll
    for (int i = 0; i < 4; ++i) {
      float v = acc[i][j] + bias;
      s += v > 0.f ? v : 0.f;
    }
    cs[j] = s;
  }
#pragma unroll
  for (int j = 0; j < 4; ++j) red[ty][tx * 4 + j] = cs[j];
  __syncthreads();
  if (tid < 64) {
    float s = 0.f;
#pragma unroll
    for (int t = 0; t < 16; ++t) s += red[t][tid];
    atomicAdd(&rout[b * DD + n0 + tid], s);
  }
}

// ---------- final MLP: out = relu(m @ Wm + bm) @ Wo + bo, m built from r1,r2 ----------
__global__ void mlp_kernel(const float* __restrict__ r1, const float* __restrict__ r2,
                           const float* __restrict__ Wm, const float* __restrict__ bm,
                           const float* __restrict__ Wo, const float* __restrict__ bo,
                           float* __restrict__ out) {
  const int b = blockIdx.x, tid = threadIdx.x;
  __shared__ float ms[1024];
  __shared__ float hs[512];
  __shared__ float red[256];
  float v1 = r1[b * DD + tid], v2 = r2[b * DD + tid];
  ms[tid] = v1; ms[256 + tid] = v2; ms[512 + tid] = v1 * v2; ms[768 + tid] = v1 - v2;
  __syncthreads();
#pragma unroll
  for (int jj = 0; jj < 2; ++jj) {
    int j = tid + jj * 256;
    float acc = bm[j];
#pragma unroll 8
    for (int k = 0; k < 1024; ++k) acc += ms[k] * Wm[(size_t)k * MM + j];
    hs[j] = acc > 0.f ? acc : 0.f;
  }
  __syncthreads();
  for (int o = 0; o < 3; ++o) {
    float s = 0.f;
    for (int k = tid; k < MM; k += 256) s += hs[k] * Wo[k * 3 + o];
    red[tid] = s; __syncthreads();
    for (int st = 128; st > 0; st >>= 1) {
      if (tid < st) red[tid] += red[tid + st];
      __syncthreads();
    }
    if (tid == 0) out[b * 3 + o] = red[0] + bo[o];
    __syncthreads();
  }
}

extern "C" void kernel_launch(void* const* d_in, const int* in_sizes, int n_in,
                              void* d_out, int out_size, void* d_ws, size_t ws_size,
                              hipStream_t stream) {
  const float* criteria = (const float*)d_in[0];
  const float* ehr      = (const float*)d_in[1];
  const int*   cmask    = (const int*)d_in[2];
  const int*   emask    = (const int*)d_in[3];
  const float* Wa       = (const float*)d_in[4];
  const float* ba       = (const float*)d_in[5];
  const float* Wr       = (const float*)d_in[6];
  const float* br       = (const float*)d_in[7];
  const float* Wm       = (const float*)d_in[8];
  const float* bm       = (const float*)d_in[9];
  const float* Wo       = (const float*)d_in[10];
  const float* bo       = (const float*)d_in[11];
  float* out = (float*)d_out;

  char* ws = (char*)d_ws;
  // layout (bytes): cB/attc [0,16.78M), eB/atte [16.78M,83.9M), align [83.9M,151M), stats, r1, r2
  unsigned short* cB     = (unsigned short*)(ws);
  unsigned short* eB     = (unsigned short*)(ws + 16777216);
  unsigned short* alignB = (unsigned short*)(ws + 83886080);
  float* amax = (float*)(ws + 150994944);
  float* asum = (float*)(ws + 151126016);
  float* bmax = (float*)(ws + 151257088);
  float* bsum = (float*)(ws + 151781376);
  float* r1   = (float*)(ws + 152305664);
  float* r2   = (float*)(ws + 152436736);
  // att_c reuses cB region; att_e reuses eB region (dead after align_kernel)
  unsigned short* attc = cB;
  unsigned short* atte = eB;
  // total ws needed: 152,567,808 bytes (~152.6 MB)

  dim3 blk(256);
  zero_kernel<<<dim3((2 * BB * DD + 255) / 256), blk, 0, stream>>>(r1, 2 * BB * DD);
  proj_kernel<<<dim3(DD / 64, (BB * LC) / 64), blk, 0, stream>>>(criteria, Wa, ba, cB);
  proj_kernel<<<dim3(DD / 64, (BB * LE) / 64), blk, 0, stream>>>(ehr, Wa, ba, eB);
  align_kernel<<<dim3(LE / 64, LC / 64, BB), blk, 0, stream>>>(cB, eB, alignB);
  astats_kernel<<<dim3(LC, BB), blk, 0, stream>>>(alignB, emask, amax, asum);
  bstats_kernel<<<dim3(LE / 256, BB), blk, 0, stream>>>(alignB, cmask, bmax, bsum);
  attc_kernel<<<dim3(DD / 64, LC / 64, BB), blk, 0, stream>>>(alignB, ehr, emask, amax, asum, attc);
  atte_kernel<<<dim3(DD / 64, LE / 64, BB), blk, 0, stream>>>(alignB, criteria, cmask, bmax, bsum, atte);
  rsum_kernel<<<dim3(DD / 64, (BB * LC) / 64), blk, 0, stream>>>(attc, criteria, Wr, br, r1, LC);
  rsum_kernel<<<dim3(DD / 64, (BB * LE) / 64), blk, 0, stream>>>(atte, ehr, Wr, br, r2, LE);
  mlp_kernel<<<dim3(BB), blk, 0, stream>>>(r1, r2, Wm, bm, Wo, bo, out);
}

// Round 2
// 842.806 us; speedup vs baseline: 3.0625x; 3.0625x over previous
//
#include <hip/hip_runtime.h>
#include <hip/hip_bf16.h>

#define BB 128
#define LC 256
#define LE 1024
#define DD 256
#define MM 512

typedef short bf16x8 __attribute__((ext_vector_type(8)));
typedef unsigned short u16x8 __attribute__((ext_vector_type(8)));
typedef float f32x4 __attribute__((ext_vector_type(4)));

__device__ __forceinline__ float bfu2f(unsigned short u) {
  return __uint_as_float(((unsigned int)u) << 16);
}
__device__ __forceinline__ unsigned short f2bfu(float f) {
  unsigned int x = __float_as_uint(f);
  return (unsigned short)((x + 0x7fffu + ((x >> 16) & 1u)) >> 16);
}

// LDS tile: 128 rows x 32 k (u16), row stride 40, 16B-chunk XOR swizzle.
#define LDST 40
__device__ __forceinline__ int ldsoff(int r, int q) {
  return r * LDST + ((q ^ ((r >> 2) & 3)) << 3);
}

// ---- shared MFMA inner step: 4 waves, each 64x64 = 4x4 tiles of 16x16x32 ----
__device__ __forceinline__ void mma_step(const unsigned short* As, const unsigned short* Bs,
                                         f32x4 (&acc)[4][4], int wm, int wn, int lane) {
  const int lm = lane & 15, quad = lane >> 4;
  bf16x8 a[4], b[4];
#pragma unroll
  for (int i = 0; i < 4; ++i) {
    int r = wm * 64 + i * 16 + lm;
    a[i] = *(const bf16x8*)&As[ldsoff(r, quad)];
    int n = wn * 64 + i * 16 + lm;
    b[i] = *(const bf16x8*)&Bs[ldsoff(n, quad)];
  }
#pragma unroll
  for (int i = 0; i < 4; ++i)
#pragma unroll
    for (int j = 0; j < 4; ++j)
      acc[i][j] = __builtin_amdgcn_mfma_f32_16x16x32_bf16(a[i], b[j], acc[i][j], 0, 0, 0);
}

// ---- natural staging: bf16 source rows [r][k], 128x32 tile ----
__device__ __forceinline__ void stage_bf16(unsigned short* S, const unsigned short* g,
                                           long ld, int tid) {
#pragma unroll
  for (int i = 0; i < 2; ++i) {
    int c = tid + i * 256;
    int r = c >> 2, q = c & 3;
    u16x8 v = *(const u16x8*)(g + (long)r * ld + q * 8);
    *(u16x8*)&S[ldsoff(r, q)] = v;
  }
}

// ---- natural staging with fp32 -> bf16 convert ----
__device__ __forceinline__ void stage_f32(unsigned short* S, const float* g, long ld, int tid) {
#pragma unroll
  for (int i = 0; i < 2; ++i) {
    int c = tid + i * 256;
    int r = c >> 2, q = c & 3;
    const float4* p = (const float4*)(g + (long)r * ld + q * 8);
    float4 v0 = p[0], v1 = p[1];
    u16x8 o;
    o[0] = f2bfu(v0.x); o[1] = f2bfu(v0.y); o[2] = f2bfu(v0.z); o[3] = f2bfu(v0.w);
    o[4] = f2bfu(v1.x); o[5] = f2bfu(v1.y); o[6] = f2bfu(v1.z); o[7] = f2bfu(v1.w);
    *(u16x8*)&S[ldsoff(r, q)] = o;
  }
}

// ---- scatter-transpose staging: fp32 source src[k][n-range], build Bt[n][k] ----
__device__ __forceinline__ void stage_f32_T(unsigned short* S, const float* src, long ld, int tid) {
  const int dcc = tid & 7, er = tid >> 3;  // er in [0,32)
#pragma unroll
  for (int i = 0; i < 4; ++i) {
    int nch = dcc + i * 8;  // 0..31 (float4 chunk of n)
    float4 v = *(const float4*)(src + (long)er * ld + nch * 4);
    float vv[4] = {v.x, v.y, v.z, v.w};
#pragma unroll
    for (int q = 0; q < 4; ++q) {
      int n = nch * 4 + q;
      S[ldsoff(n, er >> 3) + (er & 7)] = f2bfu(vv[q]);
    }
  }
}

// ---- zero fill ----
__global__ void zero_kernel(float* __restrict__ p, int n) {
  int i = blockIdx.x * 256 + threadIdx.x;
  if (i < n) p[i] = 0.f;
}

// ---- weight transpose+convert: WaT[n][k]=Wa[k][n], WrT[n][k]=Wr[k][n] ----
__global__ void wconv_kernel(const float* __restrict__ Wa, const float* __restrict__ Wr,
                             unsigned short* __restrict__ WaT, unsigned short* __restrict__ WrT) {
  int i = blockIdx.x * 256 + threadIdx.x;
  if (i < 65536) WaT[i] = f2bfu(Wa[(i & 255) * 256 + (i >> 8)]);
  if (i < 131072) WrT[i] = f2bfu(Wr[(long)(i & 511) * 256 + (i >> 9)]);
}

// ---- proj: out = relu(A @ Wa + ba) -> bf16. A fp32 [M][256], WaT bf16 [256][256] ----
__global__ __launch_bounds__(256, 2) void proj_mfma(const float* __restrict__ A,
                                                    const unsigned short* __restrict__ WaT,
                                                    const float* __restrict__ ba,
                                                    unsigned short* __restrict__ out) {
  __shared__ unsigned short As[128 * LDST], Bs[128 * LDST];
  const int tid = threadIdx.x, lane = tid & 63, w = tid >> 6, wm = w >> 1, wn = w & 1;
  const long m0 = (long)blockIdx.y * 128;
  const int n0 = blockIdx.x * 128;
  f32x4 acc[4][4] = {};
  for (int k0 = 0; k0 < DD; k0 += 32) {
    stage_f32(As, A + m0 * DD + k0, DD, tid);
    stage_bf16(Bs, WaT + (long)n0 * DD + k0, DD, tid);
    __syncthreads();
    mma_step(As, Bs, acc, wm, wn, lane);
    __syncthreads();
  }
  const int lm = lane & 15, quad = lane >> 4;
#pragma unroll
  for (int i = 0; i < 4; ++i)
#pragma unroll
    for (int j = 0; j < 4; ++j) {
      int col = n0 + wn * 64 + j * 16 + lm;
      float bias = ba[col];
#pragma unroll
      for (int r = 0; r < 4; ++r) {
        long row = m0 + wm * 64 + i * 16 + quad * 4 + r;
        float v = acc[i][j][r] + bias;
        out[row * DD + col] = f2bfu(v > 0.f ? v : 0.f);
      }
    }
}

// ---- align[b,l,e] = c[b,l,:] . e[b,e,:] ----
__global__ __launch_bounds__(256, 2) void align_mfma(const unsigned short* __restrict__ cB,
                                                     const unsigned short* __restrict__ eB,
                                                     unsigned short* __restrict__ alignB) {
  __shared__ unsigned short As[128 * LDST], Bs[128 * LDST];
  const int tid = threadIdx.x, lane = tid & 63, w = tid >> 6, wm = w >> 1, wn = w & 1;
  const int b = blockIdx.z, m0 = blockIdx.y * 128, n0 = blockIdx.x * 128;
  const unsigned short* Ag = cB + ((long)b * LC + m0) * DD;
  const unsigned short* Bg = eB + ((long)b * LE + n0) * DD;
  f32x4 acc[4][4] = {};
  for (int k0 = 0; k0 < DD; k0 += 32) {
    stage_bf16(As, Ag + k0, DD, tid);
    stage_bf16(Bs, Bg + k0, DD, tid);
    __syncthreads();
    mma_step(As, Bs, acc, wm, wn, lane);
    __syncthreads();
  }
  const int lm = lane & 15, quad = lane >> 4;
#pragma unroll
  for (int i = 0; i < 4; ++i)
#pragma unroll
    for (int j = 0; j < 4; ++j) {
      int col = n0 + wn * 64 + j * 16 + lm;
#pragma unroll
      for (int r = 0; r < 4; ++r) {
        int row = m0 + wm * 64 + i * 16 + quad * 4 + r;
        alignB[((long)b * LC + row) * LE + col] = f2bfu(acc[i][j][r]);
      }
    }
}

// ---- alpha stats (unchanged) ----
__global__ void astats_kernel(const unsigned short* __restrict__ alignB,
                              const int* __restrict__ em,
                              float* __restrict__ amax, float* __restrict__ asum) {
  const int b = blockIdx.y, l = blockIdx.x, tid = threadIdx.x;
  const unsigned short* row = alignB + ((size_t)b * LC + l) * LE;
  const int* emb = em + b * LE;
  float vals[4];
  float m = -1e30f;
#pragma unroll
  for (int i = 0; i < 4; ++i) {
    int e = tid + i * 256;
    float v = bfu2f(row[e]) + (emb[e] ? 0.f : -1e9f);
    vals[i] = v;
    m = fmaxf(m, v);
  }
  __shared__ float red[256];
  red[tid] = m; __syncthreads();
  for (int s = 128; s > 0; s >>= 1) {
    if (tid < s) red[tid] = fmaxf(red[tid], red[tid + s]);
    __syncthreads();
  }
  m = red[0];
  __syncthreads();
  float s = 0.f;
#pragma unroll
  for (int i = 0; i < 4; ++i) s += __expf(vals[i] - m);
  red[tid] = s; __syncthreads();
  for (int st = 128; st > 0; st >>= 1) {
    if (tid < st) red[tid] += red[tid + st];
    __syncthreads();
  }
  if (tid == 0) { amax[b * LC + l] = m; asum[b * LC + l] = red[0]; }
}

// ---- beta stats (unchanged) ----
__global__ void bstats_kernel(const unsigned short* __restrict__ alignB,
                              const int* __restrict__ cm,
                              float* __restrict__ bmax, float* __restrict__ bsum) {
  const int b = blockIdx.y;
  const int e = blockIdx.x * 256 + threadIdx.x;
  const int* cmb = cm + b * LC;
  float m = -1e30f, s = 0.f;
  for (int l = 0; l < LC; ++l) {
    float v = bfu2f(alignB[((size_t)b * LC + l) * LE + e]) + (cmb[l] ? 0.f : -1e9f);
    if (v > m) { s = s * __expf(m - v) + 1.f; m = v; }
    else s += __expf(v - m);
  }
  bmax[b * LE + e] = m;
  bsum[b * LE + e] = s;
}

// ---- att_c = alpha @ ehr ----
__global__ __launch_bounds__(256, 2) void attc_mfma(const unsigned short* __restrict__ alignB,
                                                    const float* __restrict__ ehr,
                                                    const int* __restrict__ em,
                                                    const float* __restrict__ amax,
                                                    const float* __restrict__ asum,
                                                    unsigned short* __restrict__ attc) {
  __shared__ unsigned short As[128 * LDST], Bs[128 * LDST];
  const int tid = threadIdx.x, lane = tid & 63, w = tid >> 6, wm = w >> 1, wn = w & 1;
  const int b = blockIdx.z, m0 = blockIdx.y * 128, n0 = blockIdx.x * 128;
  f32x4 acc[4][4] = {};
  for (int k0 = 0; k0 < LE; k0 += 32) {
    // A: alpha tile (rows l, k = e) with exp transform
#pragma unroll
    for (int i = 0; i < 2; ++i) {
      int c = tid + i * 256;
      int r = c >> 2, q = c & 3;
      int gl = m0 + r;
      float mx = amax[b * LC + gl];
      float rs = 1.f / asum[b * LC + gl];
      u16x8 v = *(const u16x8*)&alignB[((long)b * LC + gl) * LE + k0 + q * 8];
      int eb = b * LE + k0 + q * 8;
      int4 ma = *(const int4*)&em[eb];
      int4 mb = *(const int4*)&em[eb + 4];
      int mk[8] = {ma.x, ma.y, ma.z, ma.w, mb.x, mb.y, mb.z, mb.w};
      u16x8 o;
#pragma unroll
      for (int j = 0; j < 8; ++j)
        o[j] = f2bfu(__expf(bfu2f(v[j]) + (mk[j] ? 0.f : -1e9f) - mx) * rs);
      *(u16x8*)&As[ldsoff(r, q)] = o;
    }
    // B: ehr^T tile (rows n=d, k = e) scatter
    stage_f32_T(Bs, ehr + ((long)b * LE + k0) * DD + n0, DD, tid);
    __syncthreads();
    mma_step(As, Bs, acc, wm, wn, lane);
    __syncthreads();
  }
  const int lm = lane & 15, quad = lane >> 4;
#pragma unroll
  for (int i = 0; i < 4; ++i)
#pragma unroll
    for (int j = 0; j < 4; ++j) {
      int col = n0 + wn * 64 + j * 16 + lm;
#pragma unroll
      for (int r = 0; r < 4; ++r) {
        int row = m0 + wm * 64 + i * 16 + quad * 4 + r;
        attc[((long)b * LC + row) * DD + col] = f2bfu(acc[i][j][r]);
      }
    }
}

// ---- att_e = beta^T @ criteria ----
__global__ __launch_bounds__(256, 2) void atte_mfma(const unsigned short* __restrict__ alignB,
                                                    const float* __restrict__ criteria,
                                                    const int* __restrict__ cm,
                                                    const float* __restrict__ bmax,
                                                    const float* __restrict__ bsum,
                                                    unsigned short* __restrict__ atte) {
  __shared__ unsigned short As[128 * LDST], Bs[128 * LDST];
  const int tid = threadIdx.x, lane = tid & 63, w = tid >> 6, wm = w >> 1, wn = w & 1;
  const int b = blockIdx.z, m0 = blockIdx.y * 128, n0 = blockIdx.x * 128;
  f32x4 acc[4][4] = {};
  for (int k0 = 0; k0 < LC; k0 += 32) {
    // A: beta^T tile (rows e, k = l), scatter with exp transform
#pragma unroll
    for (int i = 0; i < 2; ++i) {
      int c = tid + i * 256;
      int ec = c & 15, lr = c >> 4;
      int gl = k0 + lr;
      float msk = cm[b * LC + gl] ? 0.f : -1e9f;
      u16x8 v = *(const u16x8*)&alignB[((long)b * LC + gl) * LE + m0 + ec * 8];
      int ebase = b * LE + m0 + ec * 8;
      float4 xa = *(const float4*)&bmax[ebase];
      float4 xb = *(const float4*)&bmax[ebase + 4];
      float4 sa = *(const float4*)&bsum[ebase];
      float4 sb = *(const float4*)&bsum[ebase + 4];
      float mx[8] = {xa.x, xa.y, xa.z, xa.w, xb.x, xb.y, xb.z, xb.w};
      float sm[8] = {sa.x, sa.y, sa.z, sa.w, sb.x, sb.y, sb.z, sb.w};
#pragma unroll
      for (int j = 0; j < 8; ++j) {
        int el = ec * 8 + j;
        As[ldsoff(el, lr >> 3) + (lr & 7)] =
            f2bfu(__expf(bfu2f(v[j]) + msk - mx[j]) * (1.f / sm[j]));
      }
    }
    // B: criteria^T tile (rows n=d, k = l) scatter
    stage_f32_T(Bs, criteria + ((long)b * LC + k0) * DD + n0, DD, tid);
    __syncthreads();
    mma_step(As, Bs, acc, wm, wn, lane);
    __syncthreads();
  }
  const int lm = lane & 15, quad = lane >> 4;
#pragma unroll
  for (int i = 0; i < 4; ++i)
#pragma unroll
    for (int j = 0; j < 4; ++j) {
      int col = n0 + wn * 64 + j * 16 + lm;
#pragma unroll
      for (int r = 0; r < 4; ++r) {
        int row = m0 + wm * 64 + i * 16 + quad * 4 + r;
        atte[((long)b * LE + row) * DD + col] = f2bfu(acc[i][j][r]);
      }
    }
}

// ---- r = sum_seq relu([att | orig] @ Wr + br) ----
__global__ __launch_bounds__(256, 2) void rsum_mfma(const unsigned short* __restrict__ att,
                                                    const float* __restrict__ orig,
                                                    const unsigned short* __restrict__ WrT,
                                                    const float* __restrict__ br,
                                                    float* __restrict__ rout, int Lseq) {
  __shared__ unsigned short As[128 * LDST], Bs[128 * LDST];
  __shared__ float red[2][128];
  const int tid = threadIdx.x, lane = tid & 63, w = tid >> 6, wm = w >> 1, wn = w & 1;
  const long m0 = (long)blockIdx.y * 128;
  const int n0 = blockIdx.x * 128;
  const int b = (int)(m0 / Lseq);
  f32x4 acc[4][4] = {};
  for (int k0 = 0; k0 < 2 * DD; k0 += 32) {
    if (k0 < DD)
      stage_bf16(As, att + m0 * DD + k0, DD, tid);
    else
      stage_f32(As, orig + m0 * DD + (k0 - DD), DD, tid);
    stage_bf16(Bs, WrT + (long)n0 * (2 * DD) + k0, 2 * DD, tid);
    __syncthreads();
    mma_step(As, Bs, acc, wm, wn, lane);
    __syncthreads();
  }
  const int lm = lane & 15, quad = lane >> 4;
#pragma unroll
  for (int j = 0; j < 4; ++j) {
    int col = n0 + wn * 64 + j * 16 + lm;
    float bias = br[col];
    float s = 0.f;
#pragma unroll
    for (int i = 0; i < 4; ++i)
#pragma unroll
      for (int r = 0; r < 4; ++r) {
        float v = acc[i][j][r] + bias;
        s += v > 0.f ? v : 0.f;
      }
    s += __shfl_xor(s, 16);
    s += __shfl_xor(s, 32);
    if (quad == 0) red[wm][wn * 64 + j * 16 + lm] = s;
  }
  __syncthreads();
  if (tid < 128)
    atomicAdd(&rout[b * DD + n0 + tid], red[0][tid] + red[1][tid]);
}

// ---- final MLP (unchanged) ----
__global__ void mlp_kernel(const float* __restrict__ r1, const float* __restrict__ r2,
                           const float* __restrict__ Wm, const float* __restrict__ bm,
                           const float* __restrict__ Wo, const float* __restrict__ bo,
                           float* __restrict__ out) {
  const int b = blockIdx.x, tid = threadIdx.x;
  __shared__ float ms[1024];
  __shared__ float hs[512];
  __shared__ float red[256];
  float v1 = r1[b * DD + tid], v2 = r2[b * DD + tid];
  ms[tid] = v1; ms[256 + tid] = v2; ms[512 + tid] = v1 * v2; ms[768 + tid] = v1 - v2;
  __syncthreads();
#pragma unroll
  for (int jj = 0; jj < 2; ++jj) {
    int j = tid + jj * 256;
    float acc = bm[j];
#pragma unroll 8
    for (int k = 0; k < 1024; ++k) acc += ms[k] * Wm[(size_t)k * MM + j];
    hs[j] = acc > 0.f ? acc : 0.f;
  }
  __syncthreads();
  for (int o = 0; o < 3; ++o) {
    float s = 0.f;
    for (int k = tid; k < MM; k += 256) s += hs[k] * Wo[k * 3 + o];
    red[tid] = s; __syncthreads();
    for (int st = 128; st > 0; st >>= 1) {
      if (tid < st) red[tid] += red[tid + st];
      __syncthreads();
    }
    if (tid == 0) out[b * 3 + o] = red[0] + bo[o];
    __syncthreads();
  }
}

extern "C" void kernel_launch(void* const* d_in, const int* in_sizes, int n_in,
                              void* d_out, int out_size, void* d_ws, size_t ws_size,
                              hipStream_t stream) {
  const float* criteria = (const float*)d_in[0];
  const float* ehr      = (const float*)d_in[1];
  const int*   cmask    = (const int*)d_in[2];
  const int*   emask    = (const int*)d_in[3];
  const float* Wa       = (const float*)d_in[4];
  const float* ba       = (const float*)d_in[5];
  const float* Wr       = (const float*)d_in[6];
  const float* br       = (const float*)d_in[7];
  const float* Wm       = (const float*)d_in[8];
  const float* bm       = (const float*)d_in[9];
  const float* Wo       = (const float*)d_in[10];
  const float* bo       = (const float*)d_in[11];
  float* out = (float*)d_out;

  char* ws = (char*)d_ws;
  unsigned short* cB     = (unsigned short*)(ws);              // 16.78 MB
  unsigned short* eB     = (unsigned short*)(ws + 16777216);   // 67.1 MB
  unsigned short* alignB = (unsigned short*)(ws + 83886080);   // 67.1 MB
  float* amax = (float*)(ws + 150994944);
  float* asum = (float*)(ws + 151126016);
  float* bmax = (float*)(ws + 151257088);
  float* bsum = (float*)(ws + 151781376);
  float* r1   = (float*)(ws + 152305664);
  float* r2   = (float*)(ws + 152436736);
  unsigned short* WaT = (unsigned short*)(ws + 152567808);     // 131072 B
  unsigned short* WrT = (unsigned short*)(ws + 152698880);     // 262144 B
  // total: 152,961,024 bytes
  unsigned short* attc = cB;  // reuse (dead after align)
  unsigned short* atte = eB;  // reuse (dead after align)

  dim3 blk(256);
  zero_kernel<<<dim3(256), blk, 0, stream>>>(r1, 2 * BB * DD);
  wconv_kernel<<<dim3(512), blk, 0, stream>>>(Wa, Wr, WaT, WrT);
  proj_mfma<<<dim3(2, (BB * LC) / 128), blk, 0, stream>>>(criteria, WaT, ba, cB);
  proj_mfma<<<dim3(2, (BB * LE) / 128), blk, 0, stream>>>(ehr, WaT, ba, eB);
  align_mfma<<<dim3(LE / 128, LC / 128, BB), blk, 0, stream>>>(cB, eB, alignB);
  astats_kernel<<<dim3(LC, BB), blk, 0, stream>>>(alignB, emask, amax, asum);
  bstats_kernel<<<dim3(LE / 256, BB), blk, 0, stream>>>(alignB, cmask, bmax, bsum);
  attc_mfma<<<dim3(DD / 128, LC / 128, BB), blk, 0, stream>>>(alignB, ehr, emask, amax, asum, attc);
  atte_mfma<<<dim3(DD / 128, LE / 128, BB), blk, 0, stream>>>(alignB, criteria, cmask, bmax, bsum, atte);
  rsum_mfma<<<dim3(2, (BB * LC) / 128), blk, 0, stream>>>(attc, criteria, WrT, br, r1, LC);
  rsum_mfma<<<dim3(2, (BB * LE) / 128), blk, 0, stream>>>(atte, ehr, WrT, br, r2, LE);
  mlp_kernel<<<dim3(BB), blk, 0, stream>>>(r1, r2, Wm, bm, Wo, bo, out);
}

// Round 3
// 755.620 us; speedup vs baseline: 3.4159x; 1.1154x over previous
//
#include <hip/hip_runtime.h>
#include <hip/hip_bf16.h>

#define BB 128
#define LC 256
#define LE 1024
#define DD 256
#define MM 512

typedef short bf16x8 __attribute__((ext_vector_type(8)));
typedef unsigned short u16x8 __attribute__((ext_vector_type(8)));
typedef float f32x4 __attribute__((ext_vector_type(4)));

__device__ __forceinline__ float bfu2f(unsigned short u) {
  return __uint_as_float(((unsigned int)u) << 16);
}
__device__ __forceinline__ unsigned short f2bfu(float f) {
  unsigned int x = __float_as_uint(f);
  return (unsigned short)((x + 0x7fffu + ((x >> 16) & 1u)) >> 16);
}

// LDS tile: 128 rows x 32 k (u16), row stride 40, 16B-chunk XOR swizzle.
#define LDST 40
__device__ __forceinline__ int ldsoff(int r, int q) {
  return r * LDST + ((q ^ ((r >> 2) & 3)) << 3);
}

// ---- shared MFMA inner step: 4 waves, each 64x64 = 4x4 tiles of 16x16x32 ----
__device__ __forceinline__ void mma_step(const unsigned short* As, const unsigned short* Bs,
                                         f32x4 (&acc)[4][4], int wm, int wn, int lane) {
  const int lm = lane & 15, quad = lane >> 4;
  bf16x8 a[4], b[4];
#pragma unroll
  for (int i = 0; i < 4; ++i) {
    int r = wm * 64 + i * 16 + lm;
    a[i] = *(const bf16x8*)&As[ldsoff(r, quad)];
    int n = wn * 64 + i * 16 + lm;
    b[i] = *(const bf16x8*)&Bs[ldsoff(n, quad)];
  }
#pragma unroll
  for (int i = 0; i < 4; ++i)
#pragma unroll
    for (int j = 0; j < 4; ++j)
      acc[i][j] = __builtin_amdgcn_mfma_f32_16x16x32_bf16(a[i], b[j], acc[i][j], 0, 0, 0);
}

// ---- natural staging: bf16 source rows [r][k], 128x32 tile ----
__device__ __forceinline__ void stage_bf16(unsigned short* S, const unsigned short* g,
                                           long ld, int tid) {
#pragma unroll
  for (int i = 0; i < 2; ++i) {
    int c = tid + i * 256;
    int r = c >> 2, q = c & 3;
    u16x8 v = *(const u16x8*)(g + (long)r * ld + q * 8);
    *(u16x8*)&S[ldsoff(r, q)] = v;
  }
}

// ---- natural staging with fp32 -> bf16 convert ----
__device__ __forceinline__ void stage_f32(unsigned short* S, const float* g, long ld, int tid) {
#pragma unroll
  for (int i = 0; i < 2; ++i) {
    int c = tid + i * 256;
    int r = c >> 2, q = c & 3;
    const float4* p = (const float4*)(g + (long)r * ld + q * 8);
    float4 v0 = p[0], v1 = p[1];
    u16x8 o;
    o[0] = f2bfu(v0.x); o[1] = f2bfu(v0.y); o[2] = f2bfu(v0.z); o[3] = f2bfu(v0.w);
    o[4] = f2bfu(v1.x); o[5] = f2bfu(v1.y); o[6] = f2bfu(v1.z); o[7] = f2bfu(v1.w);
    *(u16x8*)&S[ldsoff(r, q)] = o;
  }
}

// ---- scatter-transpose staging: fp32 source src[k][n-range], build Bt[n][k] ----
__device__ __forceinline__ void stage_f32_T(unsigned short* S, const float* src, long ld, int tid) {
  const int dcc = tid & 7, er = tid >> 3;  // er in [0,32)
#pragma unroll
  for (int i = 0; i < 4; ++i) {
    int nch = dcc + i * 8;  // 0..31 (float4 chunk of n)
    float4 v = *(const float4*)(src + (long)er * ld + nch * 4);
    float vv[4] = {v.x, v.y, v.z, v.w};
#pragma unroll
    for (int q = 0; q < 4; ++q) {
      int n = nch * 4 + q;
      S[ldsoff(n, er >> 3) + (er & 7)] = f2bfu(vv[q]);
    }
  }
}

// ---- zero fill ----
__global__ void zero_kernel(float* __restrict__ p, int n) {
  int i = blockIdx.x * 256 + threadIdx.x;
  if (i < n) p[i] = 0.f;
}

// ---- weight transpose+convert: WaT[n][k]=Wa[k][n], WrT[n][k]=Wr[k][n] ----
__global__ void wconv_kernel(const float* __restrict__ Wa, const float* __restrict__ Wr,
                             unsigned short* __restrict__ WaT, unsigned short* __restrict__ WrT) {
  int i = blockIdx.x * 256 + threadIdx.x;
  if (i < 65536) WaT[i] = f2bfu(Wa[(i & 255) * 256 + (i >> 8)]);
  if (i < 131072) WrT[i] = f2bfu(Wr[(long)(i & 511) * 256 + (i >> 9)]);
}

// ---- proj: out = relu(A @ Wa + ba) -> bf16. A fp32 [M][256], WaT bf16 [256][256] ----
__global__ __launch_bounds__(256, 2) void proj_mfma(const float* __restrict__ A,
                                                    const unsigned short* __restrict__ WaT,
                                                    const float* __restrict__ ba,
                                                    unsigned short* __restrict__ out) {
  __shared__ unsigned short As[128 * LDST], Bs[128 * LDST];
  const int tid = threadIdx.x, lane = tid & 63, w = tid >> 6, wm = w >> 1, wn = w & 1;
  const long m0 = (long)blockIdx.y * 128;
  const int n0 = blockIdx.x * 128;
  f32x4 acc[4][4] = {};
  for (int k0 = 0; k0 < DD; k0 += 32) {
    stage_f32(As, A + m0 * DD + k0, DD, tid);
    stage_bf16(Bs, WaT + (long)n0 * DD + k0, DD, tid);
    __syncthreads();
    mma_step(As, Bs, acc, wm, wn, lane);
    __syncthreads();
  }
  const int lm = lane & 15, quad = lane >> 4;
#pragma unroll
  for (int i = 0; i < 4; ++i)
#pragma unroll
    for (int j = 0; j < 4; ++j) {
      int col = n0 + wn * 64 + j * 16 + lm;
      float bias = ba[col];
#pragma unroll
      for (int r = 0; r < 4; ++r) {
        long row = m0 + wm * 64 + i * 16 + quad * 4 + r;
        float v = acc[i][j][r] + bias;
        out[row * DD + col] = f2bfu(v > 0.f ? v : 0.f);
      }
    }
}

// ---- align[b,l,e] = c[b,l,:] . e[b,e,:] ----
__global__ __launch_bounds__(256, 2) void align_mfma(const unsigned short* __restrict__ cB,
                                                     const unsigned short* __restrict__ eB,
                                                     unsigned short* __restrict__ alignB) {
  __shared__ unsigned short As[128 * LDST], Bs[128 * LDST];
  const int tid = threadIdx.x, lane = tid & 63, w = tid >> 6, wm = w >> 1, wn = w & 1;
  const int b = blockIdx.z, m0 = blockIdx.y * 128, n0 = blockIdx.x * 128;
  const unsigned short* Ag = cB + ((long)b * LC + m0) * DD;
  const unsigned short* Bg = eB + ((long)b * LE + n0) * DD;
  f32x4 acc[4][4] = {};
  for (int k0 = 0; k0 < DD; k0 += 32) {
    stage_bf16(As, Ag + k0, DD, tid);
    stage_bf16(Bs, Bg + k0, DD, tid);
    __syncthreads();
    mma_step(As, Bs, acc, wm, wn, lane);
    __syncthreads();
  }
  const int lm = lane & 15, quad = lane >> 4;
#pragma unroll
  for (int i = 0; i < 4; ++i)
#pragma unroll
    for (int j = 0; j < 4; ++j) {
      int col = n0 + wn * 64 + j * 16 + lm;
#pragma unroll
      for (int r = 0; r < 4; ++r) {
        int row = m0 + wm * 64 + i * 16 + quad * 4 + r;
        alignB[((long)b * LC + row) * LE + col] = f2bfu(acc[i][j][r]);
      }
    }
}

// ---- alpha stats ----
__global__ void astats_kernel(const unsigned short* __restrict__ alignB,
                              const int* __restrict__ em,
                              float* __restrict__ amax, float* __restrict__ asum) {
  const int b = blockIdx.y, l = blockIdx.x, tid = threadIdx.x;
  const unsigned short* row = alignB + ((size_t)b * LC + l) * LE;
  const int* emb = em + b * LE;
  float vals[4];
  float m = -1e30f;
#pragma unroll
  for (int i = 0; i < 4; ++i) {
    int e = tid + i * 256;
    float v = bfu2f(row[e]) + (emb[e] ? 0.f : -1e9f);
    vals[i] = v;
    m = fmaxf(m, v);
  }
  __shared__ float red[256];
  red[tid] = m; __syncthreads();
  for (int s = 128; s > 0; s >>= 1) {
    if (tid < s) red[tid] = fmaxf(red[tid], red[tid + s]);
    __syncthreads();
  }
  m = red[0];
  __syncthreads();
  float s = 0.f;
#pragma unroll
  for (int i = 0; i < 4; ++i) s += __expf(vals[i] - m);
  red[tid] = s; __syncthreads();
  for (int st = 128; st > 0; st >>= 1) {
    if (tid < st) red[tid] += red[tid + st];
    __syncthreads();
  }
  if (tid == 0) { amax[b * LC + l] = m; asum[b * LC + l] = red[0]; }
}

// ---- beta stats ----
__global__ void bstats_kernel(const unsigned short* __restrict__ alignB,
                              const int* __restrict__ cm,
                              float* __restrict__ bmax, float* __restrict__ bsum) {
  const int b = blockIdx.y;
  const int e = blockIdx.x * 256 + threadIdx.x;
  const int* cmb = cm + b * LC;
  float m = -1e30f, s = 0.f;
  for (int l = 0; l < LC; ++l) {
    float v = bfu2f(alignB[((size_t)b * LC + l) * LE + e]) + (cmb[l] ? 0.f : -1e9f);
    if (v > m) { s = s * __expf(m - v) + 1.f; m = v; }
    else s += __expf(v - m);
  }
  bmax[b * LE + e] = m;
  bsum[b * LE + e] = s;
}

// ---- att_c = alpha @ ehr ----
__global__ __launch_bounds__(256, 2) void attc_mfma(const unsigned short* __restrict__ alignB,
                                                    const float* __restrict__ ehr,
                                                    const int* __restrict__ em,
                                                    const float* __restrict__ amax,
                                                    const float* __restrict__ asum,
                                                    unsigned short* __restrict__ attc) {
  __shared__ unsigned short As[128 * LDST], Bs[128 * LDST];
  const int tid = threadIdx.x, lane = tid & 63, w = tid >> 6, wm = w >> 1, wn = w & 1;
  const int b = blockIdx.z, m0 = blockIdx.y * 128, n0 = blockIdx.x * 128;
  f32x4 acc[4][4] = {};
  for (int k0 = 0; k0 < LE; k0 += 32) {
#pragma unroll
    for (int i = 0; i < 2; ++i) {
      int c = tid + i * 256;
      int r = c >> 2, q = c & 3;
      int gl = m0 + r;
      float mx = amax[b * LC + gl];
      float rs = 1.f / asum[b * LC + gl];
      u16x8 v = *(const u16x8*)&alignB[((long)b * LC + gl) * LE + k0 + q * 8];
      int eb = b * LE + k0 + q * 8;
      int4 ma = *(const int4*)&em[eb];
      int4 mb = *(const int4*)&em[eb + 4];
      int mk[8] = {ma.x, ma.y, ma.z, ma.w, mb.x, mb.y, mb.z, mb.w};
      u16x8 o;
#pragma unroll
      for (int j = 0; j < 8; ++j)
        o[j] = f2bfu(__expf(bfu2f(v[j]) + (mk[j] ? 0.f : -1e9f) - mx) * rs);
      *(u16x8*)&As[ldsoff(r, q)] = o;
    }
    stage_f32_T(Bs, ehr + ((long)b * LE + k0) * DD + n0, DD, tid);
    __syncthreads();
    mma_step(As, Bs, acc, wm, wn, lane);
    __syncthreads();
  }
  const int lm = lane & 15, quad = lane >> 4;
#pragma unroll
  for (int i = 0; i < 4; ++i)
#pragma unroll
    for (int j = 0; j < 4; ++j) {
      int col = n0 + wn * 64 + j * 16 + lm;
#pragma unroll
      for (int r = 0; r < 4; ++r) {
        int row = m0 + wm * 64 + i * 16 + quad * 4 + r;
        attc[((long)b * LC + row) * DD + col] = f2bfu(acc[i][j][r]);
      }
    }
}

// ---- att_e = beta^T @ criteria ----
__global__ __launch_bounds__(256, 2) void atte_mfma(const unsigned short* __restrict__ alignB,
                                                    const float* __restrict__ criteria,
                                                    const int* __restrict__ cm,
                                                    const float* __restrict__ bmax,
                                                    const float* __restrict__ bsum,
                                                    unsigned short* __restrict__ atte) {
  __shared__ unsigned short As[128 * LDST], Bs[128 * LDST];
  const int tid = threadIdx.x, lane = tid & 63, w = tid >> 6, wm = w >> 1, wn = w & 1;
  const int b = blockIdx.z, m0 = blockIdx.y * 128, n0 = blockIdx.x * 128;
  f32x4 acc[4][4] = {};
  for (int k0 = 0; k0 < LC; k0 += 32) {
#pragma unroll
    for (int i = 0; i < 2; ++i) {
      int c = tid + i * 256;
      int ec = c & 15, lr = c >> 4;
      int gl = k0 + lr;
      float msk = cm[b * LC + gl] ? 0.f : -1e9f;
      u16x8 v = *(const u16x8*)&alignB[((long)b * LC + gl) * LE + m0 + ec * 8];
      int ebase = b * LE + m0 + ec * 8;
      float4 xa = *(const float4*)&bmax[ebase];
      float4 xb = *(const float4*)&bmax[ebase + 4];
      float4 sa = *(const float4*)&bsum[ebase];
      float4 sb = *(const float4*)&bsum[ebase + 4];
      float mx[8] = {xa.x, xa.y, xa.z, xa.w, xb.x, xb.y, xb.z, xb.w};
      float sm[8] = {sa.x, sa.y, sa.z, sa.w, sb.x, sb.y, sb.z, sb.w};
#pragma unroll
      for (int j = 0; j < 8; ++j) {
        int el = ec * 8 + j;
        As[ldsoff(el, lr >> 3) + (lr & 7)] =
            f2bfu(__expf(bfu2f(v[j]) + msk - mx[j]) * (1.f / sm[j]));
      }
    }
    stage_f32_T(Bs, criteria + ((long)b * LC + k0) * DD + n0, DD, tid);
    __syncthreads();
    mma_step(As, Bs, acc, wm, wn, lane);
    __syncthreads();
  }
  const int lm = lane & 15, quad = lane >> 4;
#pragma unroll
  for (int i = 0; i < 4; ++i)
#pragma unroll
    for (int j = 0; j < 4; ++j) {
      int col = n0 + wn * 64 + j * 16 + lm;
#pragma unroll
      for (int r = 0; r < 4; ++r) {
        int row = m0 + wm * 64 + i * 16 + quad * 4 + r;
        atte[((long)b * LE + row) * DD + col] = f2bfu(acc[i][j][r]);
      }
    }
}

// ---- r = sum_seq relu([att | orig] @ Wr + br) ----
__global__ __launch_bounds__(256, 2) void rsum_mfma(const unsigned short* __restrict__ att,
                                                    const float* __restrict__ orig,
                                                    const unsigned short* __restrict__ WrT,
                                                    const float* __restrict__ br,
                                                    float* __restrict__ rout, int Lseq) {
  __shared__ unsigned short As[128 * LDST], Bs[128 * LDST];
  __shared__ float red[2][128];
  const int tid = threadIdx.x, lane = tid & 63, w = tid >> 6, wm = w >> 1, wn = w & 1;
  const long m0 = (long)blockIdx.y * 128;
  const int n0 = blockIdx.x * 128;
  const int b = (int)(m0 / Lseq);
  f32x4 acc[4][4] = {};
  for (int k0 = 0; k0 < 2 * DD; k0 += 32) {
    if (k0 < DD)
      stage_bf16(As, att + m0 * DD + k0, DD, tid);
    else
      stage_f32(As, orig + m0 * DD + (k0 - DD), DD, tid);
    stage_bf16(Bs, WrT + (long)n0 * (2 * DD) + k0, 2 * DD, tid);
    __syncthreads();
    mma_step(As, Bs, acc, wm, wn, lane);
    __syncthreads();
  }
  const int lm = lane & 15, quad = lane >> 4;
#pragma unroll
  for (int j = 0; j < 4; ++j) {
    int col = n0 + wn * 64 + j * 16 + lm;
    float bias = br[col];
    float s = 0.f;
#pragma unroll
    for (int i = 0; i < 4; ++i)
#pragma unroll
      for (int r = 0; r < 4; ++r) {
        float v = acc[i][j][r] + bias;
        s += v > 0.f ? v : 0.f;
      }
    s += __shfl_xor(s, 16);
    s += __shfl_xor(s, 32);
    if (quad == 0) red[wm][wn * 64 + j * 16 + lm] = s;
  }
  __syncthreads();
  if (tid < 128)
    atomicAdd(&rout[b * DD + n0 + tid], red[0][tid] + red[1][tid]);
}

// ---- build m = [r1 | r2 | r1*r2 | r1-r2] as bf16 [128][1024] ----
__global__ void mbuild_kernel(const float* __restrict__ r1, const float* __restrict__ r2,
                              unsigned short* __restrict__ mB) {
  int i = blockIdx.x * 256 + threadIdx.x;  // 32768 = 128*256
  int b = i >> 8, d = i & 255;
  float v1 = r1[i], v2 = r2[i];
  unsigned short* row = mB + (long)b * 1024;
  row[d] = f2bfu(v1);
  row[256 + d] = f2bfu(v2);
  row[512 + d] = f2bfu(v1 * v2);
  row[768 + d] = f2bfu(v1 - v2);
}

// ---- h = relu(m @ Wm + bm): M=128, N=512, K=1024 MFMA GEMM ----
__global__ __launch_bounds__(256, 2) void mlp_mfma(const unsigned short* __restrict__ mB,
                                                   const float* __restrict__ Wm,
                                                   const float* __restrict__ bm,
                                                   float* __restrict__ h) {
  __shared__ unsigned short As[128 * LDST], Bs[128 * LDST];
  const int tid = threadIdx.x, lane = tid & 63, w = tid >> 6, wm = w >> 1, wn = w & 1;
  const int n0 = blockIdx.x * 128;
  f32x4 acc[4][4] = {};
  for (int k0 = 0; k0 < 4 * DD; k0 += 32) {
    stage_bf16(As, mB + k0, 4 * DD, tid);
    stage_f32_T(Bs, Wm + (long)k0 * MM + n0, MM, tid);
    __syncthreads();
    mma_step(As, Bs, acc, wm, wn, lane);
    __syncthreads();
  }
  const int lm = lane & 15, quad = lane >> 4;
#pragma unroll
  for (int i = 0; i < 4; ++i)
#pragma unroll
    for (int j = 0; j < 4; ++j) {
      int col = n0 + wn * 64 + j * 16 + lm;
      float bias = bm[col];
#pragma unroll
      for (int r = 0; r < 4; ++r) {
        int row = wm * 64 + i * 16 + quad * 4 + r;  // = batch index
        float v = acc[i][j][r] + bias;
        h[(long)row * MM + col] = v > 0.f ? v : 0.f;
      }
    }
}

// ---- out = h @ Wo + bo : (128 x 3 x 512) ----
__global__ void out3_kernel(const float* __restrict__ h, const float* __restrict__ Wo,
                            const float* __restrict__ bo, float* __restrict__ out) {
  const int b = blockIdx.x, tid = threadIdx.x;
  __shared__ float red[256];
  float a[3] = {0.f, 0.f, 0.f};
  for (int k = tid; k < MM; k += 256) {
    float hv = h[(long)b * MM + k];
    a[0] += hv * Wo[k * 3 + 0];
    a[1] += hv * Wo[k * 3 + 1];
    a[2] += hv * Wo[k * 3 + 2];
  }
#pragma unroll
  for (int o = 0; o < 3; ++o) {
    red[tid] = a[o]; __syncthreads();
    for (int st = 128; st > 0; st >>= 1) {
      if (tid < st) red[tid] += red[tid + st];
      __syncthreads();
    }
    if (tid == 0) out[b * 3 + o] = red[0] + bo[o];
    __syncthreads();
  }
}

extern "C" void kernel_launch(void* const* d_in, const int* in_sizes, int n_in,
                              void* d_out, int out_size, void* d_ws, size_t ws_size,
                              hipStream_t stream) {
  const float* criteria = (const float*)d_in[0];
  const float* ehr      = (const float*)d_in[1];
  const int*   cmask    = (const int*)d_in[2];
  const int*   emask    = (const int*)d_in[3];
  const float* Wa       = (const float*)d_in[4];
  const float* ba       = (const float*)d_in[5];
  const float* Wr       = (const float*)d_in[6];
  const float* br       = (const float*)d_in[7];
  const float* Wm       = (const float*)d_in[8];
  const float* bm       = (const float*)d_in[9];
  const float* Wo       = (const float*)d_in[10];
  const float* bo       = (const float*)d_in[11];
  float* out = (float*)d_out;

  char* ws = (char*)d_ws;
  unsigned short* cB     = (unsigned short*)(ws);              // 16.78 MB
  unsigned short* eB     = (unsigned short*)(ws + 16777216);   // 67.1 MB
  unsigned short* alignB = (unsigned short*)(ws + 83886080);   // 67.1 MB
  float* amax = (float*)(ws + 150994944);
  float* asum = (float*)(ws + 151126016);
  float* bmax = (float*)(ws + 151257088);
  float* bsum = (float*)(ws + 151781376);
  float* r1   = (float*)(ws + 152305664);
  float* r2   = (float*)(ws + 152436736);
  unsigned short* WaT = (unsigned short*)(ws + 152567808);     // 131072 B
  unsigned short* WrT = (unsigned short*)(ws + 152698880);     // 262144 B
  unsigned short* mB  = (unsigned short*)(ws + 152961024);     // 262144 B
  float* hbuf         = (float*)(ws + 153223168);              // 262144 B
  // total: 153,485,312 bytes
  unsigned short* attc = cB;  // reuse (dead after align)
  unsigned short* atte = eB;  // reuse (dead after align)

  dim3 blk(256);
  zero_kernel<<<dim3(256), blk, 0, stream>>>(r1, 2 * BB * DD);
  wconv_kernel<<<dim3(512), blk, 0, stream>>>(Wa, Wr, WaT, WrT);
  proj_mfma<<<dim3(2, (BB * LC) / 128), blk, 0, stream>>>(criteria, WaT, ba, cB);
  proj_mfma<<<dim3(2, (BB * LE) / 128), blk, 0, stream>>>(ehr, WaT, ba, eB);
  align_mfma<<<dim3(LE / 128, LC / 128, BB), blk, 0, stream>>>(cB, eB, alignB);
  astats_kernel<<<dim3(LC, BB), blk, 0, stream>>>(alignB, emask, amax, asum);
  bstats_kernel<<<dim3(LE / 256, BB), blk, 0, stream>>>(alignB, cmask, bmax, bsum);
  attc_mfma<<<dim3(DD / 128, LC / 128, BB), blk, 0, stream>>>(alignB, ehr, emask, amax, asum, attc);
  atte_mfma<<<dim3(DD / 128, LE / 128, BB), blk, 0, stream>>>(alignB, criteria, cmask, bmax, bsum, atte);
  rsum_mfma<<<dim3(2, (BB * LC) / 128), blk, 0, stream>>>(attc, criteria, WrT, br, r1, LC);
  rsum_mfma<<<dim3(2, (BB * LE) / 128), blk, 0, stream>>>(atte, ehr, WrT, br, r2, LE);
  mbuild_kernel<<<dim3(BB), blk, 0, stream>>>(r1, r2, mB);
  mlp_mfma<<<dim3(MM / 128), blk, 0, stream>>>(mB, Wm, bm, hbuf);
  out3_kernel<<<dim3(BB), blk, 0, stream>>>(hbuf, Wo, bo, out);
}